// Round 22
// baseline (84.347 us; speedup 1.0000x reference)
//
#include <hip/hip_runtime.h>

#define T_ 7
#define H_ 48
#define W_ 48
#define P_ 16128      // T_*H_*W_
#define HW_ 2304

typedef __attribute__((ext_vector_type(8))) short short8;
typedef __attribute__((ext_vector_type(4))) float f32x4;
typedef __attribute__((ext_vector_type(4))) unsigned u32x4;

__device__ __forceinline__ unsigned short f2bf(float f) {
  union { float f; unsigned u; } x{f};
  unsigned r = x.u + 0x7FFFu + ((x.u >> 16) & 1u);
  return (unsigned short)(r >> 16);
}
__device__ __forceinline__ float blo(unsigned u) {
  union { unsigned u; float f; } x{u << 16};
  return x.f;
}
__device__ __forceinline__ float bhi(unsigned u) {
  union { unsigned u; float f; } x{u & 0xFFFF0000u};
  return x.f;
}
// hardware bf16 RNE pack (R3/R20/R21-proven: result goes through LDS before MFMA)
__device__ __forceinline__ unsigned cvtpk(float a, float b) {
  unsigned r;
  asm("v_cvt_pk_bf16_f32 %0, %1, %2" : "=v"(r) : "v"(a), "v"(b));
  return r;
}
__device__ __forceinline__ int xcd_swz(int bid, int nwg) {
  int cpx = nwg >> 3;
  return (bid & 7) * cpx + (bid >> 3);
}

struct Wgt { short8 b00, b01, b10, b11, b20, b21, b30, b31; };

__device__ __forceinline__ Wgt load_w(const unsigned short* base, int k, int lane) {
  const unsigned short* wp = base + (size_t)k * 4096 + lane * 8;
  Wgt w;
  w.b00 = *(const short8*)(wp);
  w.b01 = *(const short8*)(wp + 512);
  w.b10 = *(const short8*)(wp + 1024);
  w.b11 = *(const short8*)(wp + 1536);
  w.b20 = *(const short8*)(wp + 2048);
  w.b21 = *(const short8*)(wp + 2560);
  w.b30 = *(const short8*)(wp + 3072);
  w.b31 = *(const short8*)(wp + 3584);
  return w;
}

__device__ __forceinline__ void mfma8(const Wgt& W, short8 af0, short8 af1,
                                      f32x4& c0, f32x4& c1, f32x4& c2, f32x4& c3) {
  c0 = __builtin_amdgcn_mfma_f32_16x16x32_bf16(af0, W.b00, c0, 0, 0, 0);
  c0 = __builtin_amdgcn_mfma_f32_16x16x32_bf16(af1, W.b01, c0, 0, 0, 0);
  c1 = __builtin_amdgcn_mfma_f32_16x16x32_bf16(af0, W.b10, c1, 0, 0, 0);
  c1 = __builtin_amdgcn_mfma_f32_16x16x32_bf16(af1, W.b11, c1, 0, 0, 0);
  c2 = __builtin_amdgcn_mfma_f32_16x16x32_bf16(af0, W.b20, c2, 0, 0, 0);
  c2 = __builtin_amdgcn_mfma_f32_16x16x32_bf16(af1, W.b21, c2, 0, 0, 0);
  c3 = __builtin_amdgcn_mfma_f32_16x16x32_bf16(af0, W.b30, c3, 0, 0, 0);
  c3 = __builtin_amdgcn_mfma_f32_16x16x32_bf16(af1, W.b31, c3, 0, 0, 0);
}

// ---------- x [64][P] fp32 -> x_clb [P][64] bf16 ----------
__global__ void k_prep_x(const float* __restrict__ in, unsigned short* __restrict__ outb) {
  __shared__ float tile[64][65];
  int p0 = blockIdx.x * 64;
  int l = threadIdx.x & 63;
  int g = threadIdx.x >> 6;
#pragma unroll
  for (int i = 0; i < 16; ++i) {
    int c = g * 16 + i;
    tile[c][l] = in[c * P_ + p0 + l];
  }
  __syncthreads();
#pragma unroll
  for (int i = 0; i < 16; ++i) {
    int p = g * 16 + i;
    outb[(p0 + p) * 64 + l] = f2bf(tile[l][p]);
  }
}

// ---------- weights [OC][64][27] fp32 -> fragment-swizzled bf16 ----------
__global__ void k_prep_w4(const float* __restrict__ s0, const float* __restrict__ s1,
                          const float* __restrict__ s2, const float* __restrict__ s3,
                          unsigned short* __restrict__ d0, unsigned short* __restrict__ d1,
                          unsigned short* __restrict__ d2, unsigned short* __restrict__ d3) {
  int y = blockIdx.y;
  const float* w = (y == 0) ? s0 : (y == 1) ? s1 : (y == 2) ? s2 : s3;
  unsigned short* wt = (y == 0) ? d0 : (y == 1) ? d1 : (y == 2) ? d2 : d3;
  int OC = (y < 2) ? 54 : 64;
  int idx = blockIdx.x * 256 + threadIdx.x;   // < 110592
  int j = idx & 7;
  int l = (idx >> 3) & 63;
  int kc = (idx >> 9) & 1;
  int nt = (idx >> 10) & 3;
  int k = idx >> 12;
  int o = nt * 16 + (l & 15);
  int c = kc * 32 + (l >> 4) * 8 + j;
  wt[idx] = (o < OC) ? f2bf(w[(o * 64 + c) * 27 + k]) : (unsigned short)0;
}

// ---------- offset conv (R8-proven, unchanged) ----------
__global__ __launch_bounds__(256) void k_off4w(const unsigned short* __restrict__ xclb,
                                               const unsigned short* __restrict__ wAs,
                                               const float* __restrict__ boff,
                                               float* __restrict__ offt2) {
  __shared__ f32x4 red[4][4][64];
  int p0 = xcd_swz(blockIdx.x, gridDim.x) * 32;
  int t = p0 / HW_;
  int r0 = p0 - t * HW_;
  int h0r = r0 / W_;
  int w0s = r0 - h0r * W_;
  int h1r = h0r + (w0s == 32 ? 1 : 0);
  int w1s = (w0s == 32) ? 0 : w0s + 16;
  int tid = threadIdx.x;
  int lane = tid & 63, wid = tid >> 6;
  int pt = lane & 15, grp = lane >> 4;

  f32x4 zacc{0.f, 0.f, 0.f, 0.f};
  f32x4 aA0 = zacc, aA1 = zacc, aA2 = zacc, aA3 = zacc;
  f32x4 aB0 = zacc, aB1 = zacc, aB2 = zacc, aB3 = zacc;
  const short8 zero8{0, 0, 0, 0, 0, 0, 0, 0};
  int kbeg = wid * 7;

#pragma unroll
  for (int kk = 0; kk < 7; ++kk) {
    int kraw = kbeg + kk;
    int k = min(kraw, 26);
    int kt = k / 9;
    int r9 = k - kt * 9;
    int kh = r9 / 3;
    int kw = r9 - (r9 / 3) * 3;
    int t2 = t + kt - 1;
    bool tok = (kraw < 27) & ((unsigned)t2 < (unsigned)T_);
    int t2c = min(max(t2, 0), T_ - 1);

    Wgt W = load_w(wAs, k, lane);
    {
      int h2 = h0r + kh - 1;
      int w2 = w0s + pt + kw - 1;
      bool ok = tok & ((unsigned)h2 < (unsigned)H_) & ((unsigned)w2 < (unsigned)W_);
      int h2c = min(max(h2, 0), H_ - 1);
      int w2c = min(max(w2, 0), W_ - 1);
      const unsigned short* ap = xclb + ((size_t)(t2c * HW_ + h2c * W_ + w2c) * 64 + grp * 8);
      short8 a0 = *(const short8*)ap;
      short8 a1 = *(const short8*)(ap + 32);
      a0 = ok ? a0 : zero8;
      a1 = ok ? a1 : zero8;
      mfma8(W, a0, a1, aA0, aA1, aA2, aA3);
    }
    {
      int h2 = h1r + kh - 1;
      int w2 = w1s + pt + kw - 1;
      bool ok = tok & ((unsigned)h2 < (unsigned)H_) & ((unsigned)w2 < (unsigned)W_);
      int h2c = min(max(h2, 0), H_ - 1);
      int w2c = min(max(w2, 0), W_ - 1);
      const unsigned short* ap = xclb + ((size_t)(t2c * HW_ + h2c * W_ + w2c) * 64 + grp * 8);
      short8 a0 = *(const short8*)ap;
      short8 a1 = *(const short8*)(ap + 32);
      a0 = ok ? a0 : zero8;
      a1 = ok ? a1 : zero8;
      mfma8(W, a0, a1, aB0, aB1, aB2, aB3);
    }
  }

  int oc = wid * 16 + pt;
  float bb = (oc < 54) ? boff[oc] : 0.f;
  int kidx = oc >> 1, d = oc & 1;

  red[wid][0][lane] = aA0;
  red[wid][1][lane] = aA1;
  red[wid][2][lane] = aA2;
  red[wid][3][lane] = aA3;
  __syncthreads();
  {
    f32x4 s = red[0][wid][lane];
    s = s + red[1][wid][lane];
    s = s + red[2][wid][lane];
    s = s + red[3][wid][lane];
    if (oc < 54) {
#pragma unroll
      for (int r = 0; r < 4; ++r) {
        int p = p0 + grp * 4 + r;
        offt2[((size_t)kidx * P_ + p) * 2 + d] = s[r] + bb;
      }
    }
  }
  __syncthreads();
  red[wid][0][lane] = aB0;
  red[wid][1][lane] = aB1;
  red[wid][2][lane] = aB2;
  red[wid][3][lane] = aB3;
  __syncthreads();
  {
    f32x4 s = red[0][wid][lane];
    s = s + red[1][wid][lane];
    s = s + red[2][wid][lane];
    s = s + red[3][wid][lane];
    if (oc < 54) {
#pragma unroll
      for (int r = 0; r < 4; ++r) {
        int p = p0 + 16 + grp * 4 + r;
        offt2[((size_t)kidx * P_ + p) * 2 + d] = s[r] + bb;
      }
    }
  }
}

// ---------- deformable sample + conv: M=16, shfl addr broadcast, 32KB LDS ----------
template <int MODE>
__global__ __launch_bounds__(256) void k_samp16(
    const unsigned short* __restrict__ xclb, const float* __restrict__ offt2,
    const unsigned short* __restrict__ wBs, const float* __restrict__ bias,
    const float* __restrict__ resid, float* __restrict__ out32,
    unsigned short* __restrict__ outb) {
  __shared__ union LDSu {
    u32x4 raw[4][16][2][16];            // 32768 B (sA aliases each wave's block)
    f32x4 red[4][4][64];                // 16384 B (epilogue only)
  } lds;
  int p0 = xcd_swz(blockIdx.x, gridDim.x) * 16;
  int t = p0 / HW_;
  int r0 = p0 - t * HW_;
  int h_r = r0 / W_;
  int w_s = r0 - h_r * W_;              // in {0,16,32}
  int tid = threadIdx.x;
  int lane = tid & 63, wid = tid >> 6;
  int pt = lane & 15, grp = lane >> 4;
  int lq = lane >> 4;                   // point sub-index for gather mapping
  int ck16 = lane & 15;                 // chunk index for gather mapping
  // sA aliases this wave's raw block (R21-proven)
  unsigned short* sAw = (unsigned short*)&lds.raw[wid];

  f32x4 zacc{0.f, 0.f, 0.f, 0.f};
  f32x4 a0c = zacc, a1c = zacc, a2c = zacc, a3c = zacc;
  int kbeg = wid * 7;

#pragma clang loop unroll(disable)
  for (int kk = 0; kk < 7; ++kk) {
    int kraw = kbeg + kk;                 // 0..27 (27 = phantom, masked)
    int k = min(kraw, 26);
    int kt = k / 9;
    int r9 = k - kt * 9;
    int kh = r9 / 3;
    int kw = r9 - (r9 / 3) * 3;
    int t2 = t + kt - 1;
    bool tok = (kraw < 27) & ((unsigned)t2 < (unsigned)T_);
    int t2c = min(max(t2, 0), T_ - 1);

    Wgt W = load_w(wBs, k, lane);

    float2 o2 = *(const float2*)(offt2 + ((size_t)k * P_ + p0 + pt) * 2);
    float ph = (float)(h_r + kh - 1) + o2.x;
    float pw = (float)(w_s + pt + kw - 1) + o2.y;
    float hf = floorf(ph), wf = floorf(pw);
    float lh = ph - hf, lw = pw - wf;
    int h0 = (int)hf, w0i = (int)wf;
    int h1 = h0 + 1, w1 = w0i + 1;
    bool h0ok = ((unsigned)h0 < (unsigned)H_), h1ok = ((unsigned)h1 < (unsigned)H_);
    bool w0ok = ((unsigned)w0i < (unsigned)W_), w1ok = ((unsigned)w1 < (unsigned)W_);
    int h0c = min(max(h0, 0), H_ - 1), h1c = min(max(h1, 0), H_ - 1);
    int w0c = min(max(w0i, 0), W_ - 1), w1c = min(max(w1, 0), W_ - 1);
    float omlh = 1.f - lh, omlw = 1.f - lw;
    float g00 = (tok & h0ok & w0ok) ? omlh * omlw : 0.f;
    float g01 = (tok & h0ok & w1ok) ? omlh * lw : 0.f;
    float g10 = (tok & h1ok & w0ok) ? lh * omlw : 0.f;
    float g11 = (tok & h1ok & w1ok) ? lh * lw : 0.f;

    // contiguous 256B segment [ws, ws+1]; sel picks the 128B half per corner
    int ws = min(max(w0i, 0), W_ - 2);
    int sel0 = w0c - ws;              // 0/1
    int sel1 = w1c - ws;              // 0/1
    int a0addr = (t2c * HW_ + h0c * W_ + ws) * 64;
    int a1addr = (t2c * HW_ + h1c * W_ + ws) * 64;

    // broadcast segment addresses via register shuffle (point q lives in lane q)
    int s00 = __shfl(a0addr, lq),      s10 = __shfl(a1addr, lq);
    int s01 = __shfl(a0addr, 4 + lq),  s11 = __shfl(a1addr, 4 + lq);
    int s02 = __shfl(a0addr, 8 + lq),  s12 = __shfl(a1addr, 8 + lq);
    int s03 = __shfl(a0addr, 12 + lq), s13 = __shfl(a1addr, 12 + lq);

    // gather: 8 instrs x 1KB, 4 contiguous 256B segments each
    u32x4 gb0 = *(const u32x4*)(xclb + (size_t)s00 + ck16 * 8);
    u32x4 gb1 = *(const u32x4*)(xclb + (size_t)s10 + ck16 * 8);
    u32x4 gb2 = *(const u32x4*)(xclb + (size_t)s01 + ck16 * 8);
    u32x4 gb3 = *(const u32x4*)(xclb + (size_t)s11 + ck16 * 8);
    u32x4 gb4 = *(const u32x4*)(xclb + (size_t)s02 + ck16 * 8);
    u32x4 gb5 = *(const u32x4*)(xclb + (size_t)s12 + ck16 * 8);
    u32x4 gb6 = *(const u32x4*)(xclb + (size_t)s03 + ck16 * 8);
    u32x4 gb7 = *(const u32x4*)(xclb + (size_t)s13 + ck16 * 8);
    __builtin_amdgcn_wave_barrier();
    {
      int pl0 = lq, pl1 = 4 + lq, pl2 = 8 + lq, pl3 = 12 + lq;
      lds.raw[wid][pl0][0][ck16 ^ pl0] = gb0;
      lds.raw[wid][pl0][1][ck16 ^ pl0] = gb1;
      lds.raw[wid][pl1][0][ck16 ^ pl1] = gb2;
      lds.raw[wid][pl1][1][ck16 ^ pl1] = gb3;
      lds.raw[wid][pl2][0][ck16 ^ pl2] = gb4;
      lds.raw[wid][pl2][1][ck16 ^ pl2] = gb5;
      lds.raw[wid][pl3][0][ck16 ^ pl3] = gb6;
      lds.raw[wid][pl3][1][ck16 ^ pl3] = gb7;
    }
    __builtin_amdgcn_wave_barrier();

    // read back this lane's corner pieces
    int b0 = sel0 * 8 + 2 * grp;
    int b1 = sel1 * 8 + 2 * grp;
    u32x4 A0 = lds.raw[wid][pt][0][(b0) ^ pt];
    u32x4 A1 = lds.raw[wid][pt][0][(b0 + 1) ^ pt];
    u32x4 B0 = lds.raw[wid][pt][0][(b1) ^ pt];
    u32x4 B1 = lds.raw[wid][pt][0][(b1 + 1) ^ pt];
    u32x4 C0 = lds.raw[wid][pt][1][(b0) ^ pt];
    u32x4 C1 = lds.raw[wid][pt][1][(b0 + 1) ^ pt];
    u32x4 D0 = lds.raw[wid][pt][1][(b1) ^ pt];
    u32x4 D1 = lds.raw[wid][pt][1][(b1 + 1) ^ pt];
    __builtin_amdgcn_wave_barrier();

#define LERPU(a, b, c, d)                                                   \
  cvtpk(g00 * blo(a) + g01 * blo(b) + g10 * blo(c) + g11 * blo(d),          \
        g00 * bhi(a) + g01 * bhi(b) + g10 * bhi(c) + g11 * bhi(d))
    u32x4 v0, v1;
    v0[0] = LERPU(A0[0], B0[0], C0[0], D0[0]);
    v0[1] = LERPU(A0[1], B0[1], C0[1], D0[1]);
    v0[2] = LERPU(A0[2], B0[2], C0[2], D0[2]);
    v0[3] = LERPU(A0[3], B0[3], C0[3], D0[3]);
    v1[0] = LERPU(A1[0], B1[0], C1[0], D1[0]);
    v1[1] = LERPU(A1[1], B1[1], C1[1], D1[1]);
    v1[2] = LERPU(A1[2], B1[2], C1[2], D1[2]);
    v1[3] = LERPU(A1[3], B1[3], C1[3], D1[3]);
#undef LERPU

    // fragment exchange in the (now dead) raw block of this wave (R21-proven)
    __builtin_amdgcn_wave_barrier();
    *(u32x4*)&sAw[pt * 72 + grp * 16] = v0;
    *(u32x4*)&sAw[pt * 72 + grp * 16 + 8] = v1;
    __builtin_amdgcn_wave_barrier();
    short8 af0 = *(const short8*)&sAw[pt * 72 + grp * 8];
    short8 af1 = *(const short8*)&sAw[pt * 72 + 32 + grp * 8];
    __builtin_amdgcn_wave_barrier();

    mfma8(W, af0, af1, a0c, a1c, a2c, a3c);
  }

  int ch = wid * 16 + pt;
  float bb = bias[ch];

  __syncthreads();                       // loop LDS (raw/sA) dead before red reuse
  lds.red[wid][0][lane] = a0c;
  lds.red[wid][1][lane] = a1c;
  lds.red[wid][2][lane] = a2c;
  lds.red[wid][3][lane] = a3c;
  __syncthreads();
  {
    f32x4 s = lds.red[0][wid][lane];
    s = s + lds.red[1][wid][lane];
    s = s + lds.red[2][wid][lane];
    s = s + lds.red[3][wid][lane];
#pragma unroll
    for (int r = 0; r < 4; ++r) {
      int p = p0 + grp * 4 + r;
      float v = s[r] + bb;
      if (MODE == 0) {
        v = (v >= 0.f) ? v : 0.1f * v;
        outb[(size_t)p * 64 + ch] = f2bf(v);
      } else {
        out32[(size_t)ch * P_ + p] = v + resid[(size_t)ch * P_ + p];
      }
    }
  }
}

extern "C" void kernel_launch(void* const* d_in, const int* in_sizes, int n_in,
                              void* d_out, int out_size, void* d_ws, size_t ws_size,
                              hipStream_t stream) {
  const float* x      = (const float*)d_in[0];
  const float* w_off0 = (const float*)d_in[1];
  const float* b_off0 = (const float*)d_in[2];
  const float* w0     = (const float*)d_in[3];
  const float* b0     = (const float*)d_in[4];
  const float* w_off1 = (const float*)d_in[5];
  const float* b_off1 = (const float*)d_in[6];
  const float* w1     = (const float*)d_in[7];
  const float* b1     = (const float*)d_in[8];
  float* out = (float*)d_out;

  char* base = (char*)d_ws;
  unsigned short* x_clb = (unsigned short*)base;               // 2,064,384 B
  unsigned short* h_clb = (unsigned short*)(base + 2064384);   // 2,064,384 B
  float*          offt2 = (float*)(base + 4128768);            // 3,483,648 B
  unsigned short* wA0   = (unsigned short*)(base + 7612416);   // 221,184 B
  unsigned short* wA1   = (unsigned short*)(base + 7833600);
  unsigned short* wB0   = (unsigned short*)(base + 8054784);
  unsigned short* wB1   = (unsigned short*)(base + 8275968);   // end ~8.5 MB

  hipLaunchKernelGGL(k_prep_x, dim3(252), dim3(256), 0, stream, x, x_clb);
  hipLaunchKernelGGL(k_prep_w4, dim3(432, 4), dim3(256), 0, stream,
                     w_off0, w_off1, w0, w1, wA0, wA1, wB0, wB1);

  // layer 0
  hipLaunchKernelGGL(k_off4w, dim3(504), dim3(256), 0, stream, x_clb, wA0, b_off0, offt2);
  hipLaunchKernelGGL((k_samp16<0>), dim3(1008), dim3(256), 0, stream,
                     x_clb, offt2, wB0, b0, (const float*)nullptr, (float*)nullptr, h_clb);

  // layer 1
  hipLaunchKernelGGL(k_off4w, dim3(504), dim3(256), 0, stream, h_clb, wA1, b_off1, offt2);
  hipLaunchKernelGGL((k_samp16<1>), dim3(1008), dim3(256), 0, stream,
                     h_clb, offt2, wB1, b1, x, out, (unsigned short*)nullptr);
}

// Round 23
// 80.831 us; speedup vs baseline: 1.0435x; 1.0435x over previous
//
#include <hip/hip_runtime.h>

#define T_ 7
#define H_ 48
#define W_ 48
#define P_ 16128      // T_*H_*W_
#define HW_ 2304

typedef __attribute__((ext_vector_type(8))) short short8;
typedef __attribute__((ext_vector_type(4))) float f32x4;
typedef __attribute__((ext_vector_type(4))) unsigned u32x4;

__device__ __forceinline__ unsigned short f2bf(float f) {
  union { float f; unsigned u; } x{f};
  unsigned r = x.u + 0x7FFFu + ((x.u >> 16) & 1u);
  return (unsigned short)(r >> 16);
}
__device__ __forceinline__ float blo(unsigned u) {
  union { unsigned u; float f; } x{u << 16};
  return x.f;
}
__device__ __forceinline__ float bhi(unsigned u) {
  union { unsigned u; float f; } x{u & 0xFFFF0000u};
  return x.f;
}
// hardware bf16 RNE pack (R3/R20/R21-proven: result goes through LDS before MFMA)
__device__ __forceinline__ unsigned cvtpk(float a, float b) {
  unsigned r;
  asm("v_cvt_pk_bf16_f32 %0, %1, %2" : "=v"(r) : "v"(a), "v"(b));
  return r;
}
__device__ __forceinline__ int xcd_swz(int bid, int nwg) {
  int cpx = nwg >> 3;
  return (bid & 7) * cpx + (bid >> 3);
}

struct Wgt { short8 b00, b01, b10, b11, b20, b21, b30, b31; };

__device__ __forceinline__ Wgt load_w(const unsigned short* base, int k, int lane) {
  const unsigned short* wp = base + (size_t)k * 4096 + lane * 8;
  Wgt w;
  w.b00 = *(const short8*)(wp);
  w.b01 = *(const short8*)(wp + 512);
  w.b10 = *(const short8*)(wp + 1024);
  w.b11 = *(const short8*)(wp + 1536);
  w.b20 = *(const short8*)(wp + 2048);
  w.b21 = *(const short8*)(wp + 2560);
  w.b30 = *(const short8*)(wp + 3072);
  w.b31 = *(const short8*)(wp + 3584);
  return w;
}

__device__ __forceinline__ void mfma8(const Wgt& W, short8 af0, short8 af1,
                                      f32x4& c0, f32x4& c1, f32x4& c2, f32x4& c3) {
  c0 = __builtin_amdgcn_mfma_f32_16x16x32_bf16(af0, W.b00, c0, 0, 0, 0);
  c0 = __builtin_amdgcn_mfma_f32_16x16x32_bf16(af1, W.b01, c0, 0, 0, 0);
  c1 = __builtin_amdgcn_mfma_f32_16x16x32_bf16(af0, W.b10, c1, 0, 0, 0);
  c1 = __builtin_amdgcn_mfma_f32_16x16x32_bf16(af1, W.b11, c1, 0, 0, 0);
  c2 = __builtin_amdgcn_mfma_f32_16x16x32_bf16(af0, W.b20, c2, 0, 0, 0);
  c2 = __builtin_amdgcn_mfma_f32_16x16x32_bf16(af1, W.b21, c2, 0, 0, 0);
  c3 = __builtin_amdgcn_mfma_f32_16x16x32_bf16(af0, W.b30, c3, 0, 0, 0);
  c3 = __builtin_amdgcn_mfma_f32_16x16x32_bf16(af1, W.b31, c3, 0, 0, 0);
}

// ---------- x [64][P] fp32 -> x_clb [P][64] bf16 ----------
__global__ void k_prep_x(const float* __restrict__ in, unsigned short* __restrict__ outb) {
  __shared__ float tile[64][65];
  int p0 = blockIdx.x * 64;
  int l = threadIdx.x & 63;
  int g = threadIdx.x >> 6;
#pragma unroll
  for (int i = 0; i < 16; ++i) {
    int c = g * 16 + i;
    tile[c][l] = in[c * P_ + p0 + l];
  }
  __syncthreads();
#pragma unroll
  for (int i = 0; i < 16; ++i) {
    int p = g * 16 + i;
    outb[(p0 + p) * 64 + l] = f2bf(tile[l][p]);
  }
}

// ---------- weights [OC][64][27] fp32 -> fragment-swizzled bf16 ----------
__global__ void k_prep_w4(const float* __restrict__ s0, const float* __restrict__ s1,
                          const float* __restrict__ s2, const float* __restrict__ s3,
                          unsigned short* __restrict__ d0, unsigned short* __restrict__ d1,
                          unsigned short* __restrict__ d2, unsigned short* __restrict__ d3) {
  int y = blockIdx.y;
  const float* w = (y == 0) ? s0 : (y == 1) ? s1 : (y == 2) ? s2 : s3;
  unsigned short* wt = (y == 0) ? d0 : (y == 1) ? d1 : (y == 2) ? d2 : d3;
  int OC = (y < 2) ? 54 : 64;
  int idx = blockIdx.x * 256 + threadIdx.x;   // < 110592
  int j = idx & 7;
  int l = (idx >> 3) & 63;
  int kc = (idx >> 9) & 1;
  int nt = (idx >> 10) & 3;
  int k = idx >> 12;
  int o = nt * 16 + (l & 15);
  int c = kc * 32 + (l >> 4) * 8 + j;
  wt[idx] = (o < OC) ? f2bf(w[(o * 64 + c) * 27 + k]) : (unsigned short)0;
}

// ---------- offset conv (R8-proven, unchanged) ----------
__global__ __launch_bounds__(256) void k_off4w(const unsigned short* __restrict__ xclb,
                                               const unsigned short* __restrict__ wAs,
                                               const float* __restrict__ boff,
                                               float* __restrict__ offt2) {
  __shared__ f32x4 red[4][4][64];
  int p0 = xcd_swz(blockIdx.x, gridDim.x) * 32;
  int t = p0 / HW_;
  int r0 = p0 - t * HW_;
  int h0r = r0 / W_;
  int w0s = r0 - h0r * W_;
  int h1r = h0r + (w0s == 32 ? 1 : 0);
  int w1s = (w0s == 32) ? 0 : w0s + 16;
  int tid = threadIdx.x;
  int lane = tid & 63, wid = tid >> 6;
  int pt = lane & 15, grp = lane >> 4;

  f32x4 zacc{0.f, 0.f, 0.f, 0.f};
  f32x4 aA0 = zacc, aA1 = zacc, aA2 = zacc, aA3 = zacc;
  f32x4 aB0 = zacc, aB1 = zacc, aB2 = zacc, aB3 = zacc;
  const short8 zero8{0, 0, 0, 0, 0, 0, 0, 0};
  int kbeg = wid * 7;

#pragma unroll
  for (int kk = 0; kk < 7; ++kk) {
    int kraw = kbeg + kk;
    int k = min(kraw, 26);
    int kt = k / 9;
    int r9 = k - kt * 9;
    int kh = r9 / 3;
    int kw = r9 - (r9 / 3) * 3;
    int t2 = t + kt - 1;
    bool tok = (kraw < 27) & ((unsigned)t2 < (unsigned)T_);
    int t2c = min(max(t2, 0), T_ - 1);

    Wgt W = load_w(wAs, k, lane);
    {
      int h2 = h0r + kh - 1;
      int w2 = w0s + pt + kw - 1;
      bool ok = tok & ((unsigned)h2 < (unsigned)H_) & ((unsigned)w2 < (unsigned)W_);
      int h2c = min(max(h2, 0), H_ - 1);
      int w2c = min(max(w2, 0), W_ - 1);
      const unsigned short* ap = xclb + ((size_t)(t2c * HW_ + h2c * W_ + w2c) * 64 + grp * 8);
      short8 a0 = *(const short8*)ap;
      short8 a1 = *(const short8*)(ap + 32);
      a0 = ok ? a0 : zero8;
      a1 = ok ? a1 : zero8;
      mfma8(W, a0, a1, aA0, aA1, aA2, aA3);
    }
    {
      int h2 = h1r + kh - 1;
      int w2 = w1s + pt + kw - 1;
      bool ok = tok & ((unsigned)h2 < (unsigned)H_) & ((unsigned)w2 < (unsigned)W_);
      int h2c = min(max(h2, 0), H_ - 1);
      int w2c = min(max(w2, 0), W_ - 1);
      const unsigned short* ap = xclb + ((size_t)(t2c * HW_ + h2c * W_ + w2c) * 64 + grp * 8);
      short8 a0 = *(const short8*)ap;
      short8 a1 = *(const short8*)(ap + 32);
      a0 = ok ? a0 : zero8;
      a1 = ok ? a1 : zero8;
      mfma8(W, a0, a1, aB0, aB1, aB2, aB3);
    }
  }

  int oc = wid * 16 + pt;
  float bb = (oc < 54) ? boff[oc] : 0.f;
  int kidx = oc >> 1, d = oc & 1;

  red[wid][0][lane] = aA0;
  red[wid][1][lane] = aA1;
  red[wid][2][lane] = aA2;
  red[wid][3][lane] = aA3;
  __syncthreads();
  {
    f32x4 s = red[0][wid][lane];
    s = s + red[1][wid][lane];
    s = s + red[2][wid][lane];
    s = s + red[3][wid][lane];
    if (oc < 54) {
#pragma unroll
      for (int r = 0; r < 4; ++r) {
        int p = p0 + grp * 4 + r;
        offt2[((size_t)kidx * P_ + p) * 2 + d] = s[r] + bb;
      }
    }
  }
  __syncthreads();
  red[wid][0][lane] = aB0;
  red[wid][1][lane] = aB1;
  red[wid][2][lane] = aB2;
  red[wid][3][lane] = aB3;
  __syncthreads();
  {
    f32x4 s = red[0][wid][lane];
    s = s + red[1][wid][lane];
    s = s + red[2][wid][lane];
    s = s + red[3][wid][lane];
    if (oc < 54) {
#pragma unroll
      for (int r = 0; r < 4; ++r) {
        int p = p0 + 16 + grp * 4 + r;
        offt2[((size_t)kidx * P_ + p) * 2 + d] = s[r] + bb;
      }
    }
  }
}

// ---------- deformable sample + conv: M=16, sA aliased onto dead raw (33.3KB LDS) ----------
template <int MODE>
__global__ __launch_bounds__(256) void k_samp16(
    const unsigned short* __restrict__ xclb, const float* __restrict__ offt2,
    const unsigned short* __restrict__ wBs, const float* __restrict__ bias,
    const float* __restrict__ resid, float* __restrict__ out32,
    unsigned short* __restrict__ outb) {
  __shared__ union LDSu {
    struct {
      u32x4 raw[4][16][2][16];          // 32768 B (sA aliases each wave's block)
      int abuf[4][16][2];               // 512 B
    } lp;
    f32x4 red[4][4][64];                // 16384 B (epilogue only)
  } lds;
  int p0 = xcd_swz(blockIdx.x, gridDim.x) * 16;
  int t = p0 / HW_;
  int r0 = p0 - t * HW_;
  int h_r = r0 / W_;
  int w_s = r0 - h_r * W_;              // in {0,16,32}
  int tid = threadIdx.x;
  int lane = tid & 63, wid = tid >> 6;
  int pt = lane & 15, grp = lane >> 4;
  int lq = lane >> 4;                   // point sub-index for gather mapping
  int ck16 = lane & 15;                 // chunk index for gather mapping
  // sA aliases this wave's raw block: raw is dead once the readback completes
  // (wave-wide in-order LDS ops; wave_barriers pin compiler order)
  unsigned short* sAw = (unsigned short*)&lds.lp.raw[wid];

  f32x4 zacc{0.f, 0.f, 0.f, 0.f};
  f32x4 a0c = zacc, a1c = zacc, a2c = zacc, a3c = zacc;
  int kbeg = wid * 7;

#pragma clang loop unroll(disable)
  for (int kk = 0; kk < 7; ++kk) {
    int kraw = kbeg + kk;                 // 0..27 (27 = phantom, masked)
    int k = min(kraw, 26);
    int kt = k / 9;
    int r9 = k - kt * 9;
    int kh = r9 / 3;
    int kw = r9 - (r9 / 3) * 3;
    int t2 = t + kt - 1;
    bool tok = (kraw < 27) & ((unsigned)t2 < (unsigned)T_);
    int t2c = min(max(t2, 0), T_ - 1);

    Wgt W = load_w(wBs, k, lane);

    float2 o2 = *(const float2*)(offt2 + ((size_t)k * P_ + p0 + pt) * 2);
    float ph = (float)(h_r + kh - 1) + o2.x;
    float pw = (float)(w_s + pt + kw - 1) + o2.y;
    float hf = floorf(ph), wf = floorf(pw);
    float lh = ph - hf, lw = pw - wf;
    int h0 = (int)hf, w0i = (int)wf;
    int h1 = h0 + 1, w1 = w0i + 1;
    bool h0ok = ((unsigned)h0 < (unsigned)H_), h1ok = ((unsigned)h1 < (unsigned)H_);
    bool w0ok = ((unsigned)w0i < (unsigned)W_), w1ok = ((unsigned)w1 < (unsigned)W_);
    int h0c = min(max(h0, 0), H_ - 1), h1c = min(max(h1, 0), H_ - 1);
    int w0c = min(max(w0i, 0), W_ - 1), w1c = min(max(w1, 0), W_ - 1);
    float omlh = 1.f - lh, omlw = 1.f - lw;
    float g00 = (tok & h0ok & w0ok) ? omlh * omlw : 0.f;
    float g01 = (tok & h0ok & w1ok) ? omlh * lw : 0.f;
    float g10 = (tok & h1ok & w0ok) ? lh * omlw : 0.f;
    float g11 = (tok & h1ok & w1ok) ? lh * lw : 0.f;

    // contiguous 256B segment [ws, ws+1]; sel picks the 128B half per corner
    int ws = min(max(w0i, 0), W_ - 2);
    int sel0 = w0c - ws;              // 0/1
    int sel1 = w1c - ws;              // 0/1
    if (grp == 0) {
      lds.lp.abuf[wid][pt][0] = (t2c * HW_ + h0c * W_ + ws) * 64;
      lds.lp.abuf[wid][pt][1] = (t2c * HW_ + h1c * W_ + ws) * 64;
    }
    __builtin_amdgcn_wave_barrier();

    // gather: 8 instrs x 1KB, 4 contiguous 256B segments each
    u32x4 gb0, gb1, gb2, gb3, gb4, gb5, gb6, gb7;
    {
      int pl0 = lq, pl1 = 4 + lq, pl2 = 8 + lq, pl3 = 12 + lq;
      const unsigned short* c0p = xclb + (size_t)lds.lp.abuf[wid][pl0][0] + ck16 * 8;
      const unsigned short* c1p = xclb + (size_t)lds.lp.abuf[wid][pl0][1] + ck16 * 8;
      const unsigned short* c2p = xclb + (size_t)lds.lp.abuf[wid][pl1][0] + ck16 * 8;
      const unsigned short* c3p = xclb + (size_t)lds.lp.abuf[wid][pl1][1] + ck16 * 8;
      const unsigned short* c4p = xclb + (size_t)lds.lp.abuf[wid][pl2][0] + ck16 * 8;
      const unsigned short* c5p = xclb + (size_t)lds.lp.abuf[wid][pl2][1] + ck16 * 8;
      const unsigned short* c6p = xclb + (size_t)lds.lp.abuf[wid][pl3][0] + ck16 * 8;
      const unsigned short* c7p = xclb + (size_t)lds.lp.abuf[wid][pl3][1] + ck16 * 8;
      gb0 = *(const u32x4*)c0p;
      gb1 = *(const u32x4*)c1p;
      gb2 = *(const u32x4*)c2p;
      gb3 = *(const u32x4*)c3p;
      gb4 = *(const u32x4*)c4p;
      gb5 = *(const u32x4*)c5p;
      gb6 = *(const u32x4*)c6p;
      gb7 = *(const u32x4*)c7p;
    }
    __builtin_amdgcn_wave_barrier();
    {
      int pl0 = lq, pl1 = 4 + lq, pl2 = 8 + lq, pl3 = 12 + lq;
      lds.lp.raw[wid][pl0][0][ck16 ^ pl0] = gb0;
      lds.lp.raw[wid][pl0][1][ck16 ^ pl0] = gb1;
      lds.lp.raw[wid][pl1][0][ck16 ^ pl1] = gb2;
      lds.lp.raw[wid][pl1][1][ck16 ^ pl1] = gb3;
      lds.lp.raw[wid][pl2][0][ck16 ^ pl2] = gb4;
      lds.lp.raw[wid][pl2][1][ck16 ^ pl2] = gb5;
      lds.lp.raw[wid][pl3][0][ck16 ^ pl3] = gb6;
      lds.lp.raw[wid][pl3][1][ck16 ^ pl3] = gb7;
    }
    __builtin_amdgcn_wave_barrier();

    // read back this lane's corner pieces
    int b0 = sel0 * 8 + 2 * grp;
    int b1 = sel1 * 8 + 2 * grp;
    u32x4 A0 = lds.lp.raw[wid][pt][0][(b0) ^ pt];
    u32x4 A1 = lds.lp.raw[wid][pt][0][(b0 + 1) ^ pt];
    u32x4 B0 = lds.lp.raw[wid][pt][0][(b1) ^ pt];
    u32x4 B1 = lds.lp.raw[wid][pt][0][(b1 + 1) ^ pt];
    u32x4 C0 = lds.lp.raw[wid][pt][1][(b0) ^ pt];
    u32x4 C1 = lds.lp.raw[wid][pt][1][(b0 + 1) ^ pt];
    u32x4 D0 = lds.lp.raw[wid][pt][1][(b1) ^ pt];
    u32x4 D1 = lds.lp.raw[wid][pt][1][(b1 + 1) ^ pt];
    __builtin_amdgcn_wave_barrier();

#define LERPU(a, b, c, d)                                                   \
  cvtpk(g00 * blo(a) + g01 * blo(b) + g10 * blo(c) + g11 * blo(d),          \
        g00 * bhi(a) + g01 * bhi(b) + g10 * bhi(c) + g11 * bhi(d))
    u32x4 v0, v1;
    v0[0] = LERPU(A0[0], B0[0], C0[0], D0[0]);
    v0[1] = LERPU(A0[1], B0[1], C0[1], D0[1]);
    v0[2] = LERPU(A0[2], B0[2], C0[2], D0[2]);
    v0[3] = LERPU(A0[3], B0[3], C0[3], D0[3]);
    v1[0] = LERPU(A1[0], B1[0], C1[0], D1[0]);
    v1[1] = LERPU(A1[1], B1[1], C1[1], D1[1]);
    v1[2] = LERPU(A1[2], B1[2], C1[2], D1[2]);
    v1[3] = LERPU(A1[3], B1[3], C1[3], D1[3]);
#undef LERPU

    // fragment exchange in the (now dead) raw block of this wave
    __builtin_amdgcn_wave_barrier();
    *(u32x4*)&sAw[pt * 72 + grp * 16] = v0;
    *(u32x4*)&sAw[pt * 72 + grp * 16 + 8] = v1;
    __builtin_amdgcn_wave_barrier();
    short8 af0 = *(const short8*)&sAw[pt * 72 + grp * 8];
    short8 af1 = *(const short8*)&sAw[pt * 72 + 32 + grp * 8];
    __builtin_amdgcn_wave_barrier();

    mfma8(W, af0, af1, a0c, a1c, a2c, a3c);
  }

  int ch = wid * 16 + pt;
  float bb = bias[ch];

  __syncthreads();                       // loop LDS (raw/sA) dead before red reuse
  lds.red[wid][0][lane] = a0c;
  lds.red[wid][1][lane] = a1c;
  lds.red[wid][2][lane] = a2c;
  lds.red[wid][3][lane] = a3c;
  __syncthreads();
  {
    f32x4 s = lds.red[0][wid][lane];
    s = s + lds.red[1][wid][lane];
    s = s + lds.red[2][wid][lane];
    s = s + lds.red[3][wid][lane];
#pragma unroll
    for (int r = 0; r < 4; ++r) {
      int p = p0 + grp * 4 + r;
      float v = s[r] + bb;
      if (MODE == 0) {
        v = (v >= 0.f) ? v : 0.1f * v;
        outb[(size_t)p * 64 + ch] = f2bf(v);
      } else {
        out32[(size_t)ch * P_ + p] = v + resid[(size_t)ch * P_ + p];
      }
    }
  }
}

extern "C" void kernel_launch(void* const* d_in, const int* in_sizes, int n_in,
                              void* d_out, int out_size, void* d_ws, size_t ws_size,
                              hipStream_t stream) {
  const float* x      = (const float*)d_in[0];
  const float* w_off0 = (const float*)d_in[1];
  const float* b_off0 = (const float*)d_in[2];
  const float* w0     = (const float*)d_in[3];
  const float* b0     = (const float*)d_in[4];
  const float* w_off1 = (const float*)d_in[5];
  const float* b_off1 = (const float*)d_in[6];
  const float* w1     = (const float*)d_in[7];
  const float* b1     = (const float*)d_in[8];
  float* out = (float*)d_out;

  char* base = (char*)d_ws;
  unsigned short* x_clb = (unsigned short*)base;               // 2,064,384 B
  unsigned short* h_clb = (unsigned short*)(base + 2064384);   // 2,064,384 B
  float*          offt2 = (float*)(base + 4128768);            // 3,483,648 B
  unsigned short* wA0   = (unsigned short*)(base + 7612416);   // 221,184 B
  unsigned short* wA1   = (unsigned short*)(base + 7833600);
  unsigned short* wB0   = (unsigned short*)(base + 8054784);
  unsigned short* wB1   = (unsigned short*)(base + 8275968);   // end ~8.5 MB

  hipLaunchKernelGGL(k_prep_x, dim3(252), dim3(256), 0, stream, x, x_clb);
  hipLaunchKernelGGL(k_prep_w4, dim3(432, 4), dim3(256), 0, stream,
                     w_off0, w_off1, w0, w1, wA0, wA1, wB0, wB1);

  // layer 0
  hipLaunchKernelGGL(k_off4w, dim3(504), dim3(256), 0, stream, x_clb, wA0, b_off0, offt2);
  hipLaunchKernelGGL((k_samp16<0>), dim3(1008), dim3(256), 0, stream,
                     x_clb, offt2, wB0, b0, (const float*)nullptr, (float*)nullptr, h_clb);

  // layer 1
  hipLaunchKernelGGL(k_off4w, dim3(504), dim3(256), 0, stream, h_clb, wA1, b_off1, offt2);
  hipLaunchKernelGGL((k_samp16<1>), dim3(1008), dim3(256), 0, stream,
                     h_clb, offt2, wB1, b1, x, out, (unsigned short*)nullptr);
}